// Round 12
// baseline (7486.965 us; speedup 1.0000x reference)
//
#include <hip/hip_runtime.h>

#define NIN  512
#define NREC 2048
#define NOUT 128
#define BB   64
#define TT   250

// OUTPUTS ARE FLOAT32 (R9 probe). Semantics: JAX text (R10 PASS, absmax 0.0078).
// ---- d_ws layout (31.4 MB total; 34.5 MB verified safe) ----
#define OFF_WRT  0UL          // f32 W_r^T [n][m]      16,777,216
#define OFF_DB   16777216UL   // u8  delays [n][m]      4,194,304
#define OFF_WIT  20971520UL   // f32 W_i^T [i][m]       4,194,304
#define OFF_WOT  25165824UL   // f32 W_o^T [n][o]       1,048,576
#define OFF_MASK 26214400UL   // u32 masks [t*64+b][64] 4,096,000
#define OFF_G    30310400UL   // f64 g[b][n]            1,048,576

__device__ __forceinline__ int decode_delay(int v) {
    if (v >= 0 && v <= 4) return v;
    const float f = __int_as_float(v);
    if (f >= 0.5f && f <= 4.5f) return (int)(f + 0.5f);
    return 0;
}
__device__ __forceinline__ int delay_like(int v) {
    if (v >= 0 && v <= 4) return 1;
    const float f = __int_as_float(v);
    return (f >= 0.5f && f <= 4.5f) ? 1 : 0;
}
__device__ __forceinline__ unsigned lane_rank(unsigned long long m) {
    unsigned r = __builtin_amdgcn_mbcnt_lo((unsigned)m, 0u);
    return __builtin_amdgcn_mbcnt_hi((unsigned)(m >> 32), r);
}

__global__ __launch_bounds__(256) void k_prep(
    const void* __restrict__ c4A, const void* __restrict__ c4B,
    const float* __restrict__ Wi, const float* __restrict__ Wo,
    float* __restrict__ WrT, unsigned char* __restrict__ dBp,
    float* __restrict__ WiT, float* __restrict__ WoT)
{
    const int* iA = (const int*)c4A;
    const int* iB = (const int*)c4B;
    int cntA = 0, cntB = 0;
    for (int j = 0; j < 64; ++j) { cntA += delay_like(iA[j]); cntB += delay_like(iB[j]); }
    const int*   dl = (cntA >= cntB) ? iA : iB;
    const float* Wr = (cntA >= cntB) ? (const float*)c4B : (const float*)c4A;

    const int idx = blockIdx.x * 256 + threadIdx.x;
    if (idx < NREC * NREC) {
        const int n = idx >> 11, m = idx & 2047;
        WrT[idx] = Wr[(size_t)m * NREC + n];                 // W_rT[n][m] = W_r[m][n]
        dBp[idx] = (unsigned char)decode_delay(dl[idx]);     // delays[n][m] natural
    }
    if (idx < NIN * NREC) {
        const int i = idx >> 11, m = idx & 2047;
        WiT[idx] = Wi[(size_t)m * NIN + i];                  // W_iT[i][m]
    }
    if (idx < NREC * NOUT) {
        const int n = idx >> 7, o = idx & 127;
        WoT[idx] = Wo[(size_t)o * NREC + n];                 // W_oT[n][o]
    }
}

// R12: software-pipelined event loops — register double-buffer, batch k+1's
// loads issued BEFORE batch k's accumulation (~8 rows in flight).
__global__ __launch_bounds__(1024) void k_main(
    const float* __restrict__ x,
    const float* __restrict__ WrT, const unsigned char* __restrict__ dBp,
    const float* __restrict__ WiT,
    const float* __restrict__ Br,
    const float* __restrict__ tau_rec, const float* __restrict__ tau_out,
    const float* __restrict__ thr_rec,
    unsigned* __restrict__ spikeMask, double* __restrict__ g)
{
    __shared__ int icnt[8];
    __shared__ unsigned short ilist[NIN];
    __shared__ int zcnt[32];
    __shared__ unsigned short slist[NREC];

    const int b    = blockIdx.x;
    const int tid  = threadIdx.x;
    const int w    = tid >> 6;
    const int lane = tid & 63;

    const double rec_c = exp(-0.01 / (double)tau_rec[0]);
    const double out_c = exp(-0.01 / (double)tau_out[0]);
    const double thr   = (double)thr_rec[0];
    const double brA   = (double)Br[tid];
    const double brB   = (double)Br[tid + 1024];
    double memA = 0.0, memB = 0.0, gA = 0.0, gB = 0.0;
    double a0 = 0.0, a1 = 0.0, a2 = 0.0, a3 = 0.0;
    double c0 = 0.0, c1 = 0.0, c2 = 0.0, c3 = 0.0;

    const float* xb = x + (size_t)b * NIN * TT;
    float xv = (tid < NIN) ? xb[(size_t)tid * TT] : 0.f;

    for (int t = 0; t < TT; ++t) {
        double curA = a0; a0 = a1; a1 = a2; a2 = a3; a3 = 0.0;
        double curB = c0; c0 = c1; c1 = c2; c2 = c3; c3 = 0.0;

        unsigned long long im = 0;
        bool ihit = false;
        if (w < 8) {
            ihit = (xv != 0.f);
            im = __ballot(ihit);
            if (lane == 0) icnt[w] = __popcll(im);
        }
        float xv_next = 0.f;
        if (t + 1 < TT && tid < NIN) xv_next = xb[(size_t)tid * TT + (t + 1)];
        __syncthreads();                                  // S1

        int ioffw = 0, itot = 0;
        for (int j = 0; j < 8; ++j) { const int c = icnt[j]; if (j < w) ioffw += c; itot += c; }
        if (ihit) ilist[ioffw + lane_rank(im)] = (unsigned short)tid;
        __syncthreads();                                  // S2

        // ---- input gather: pipelined, 2 batches of 4 rows in flight ----
        {
            int k = 0;
            if (itot >= 4) {
                const float* p0 = WiT + (size_t)ilist[0] * NREC;
                const float* p1 = WiT + (size_t)ilist[1] * NREC;
                const float* p2 = WiT + (size_t)ilist[2] * NREC;
                const float* p3 = WiT + (size_t)ilist[3] * NREC;
                float A0 = p0[tid], B0 = p0[tid + 1024];
                float A1 = p1[tid], B1 = p1[tid + 1024];
                float A2 = p2[tid], B2 = p2[tid + 1024];
                float A3 = p3[tid], B3 = p3[tid + 1024];
                for (k = 4; k + 4 <= itot; k += 4) {
                    const float* q0 = WiT + (size_t)ilist[k]     * NREC;
                    const float* q1 = WiT + (size_t)ilist[k + 1] * NREC;
                    const float* q2 = WiT + (size_t)ilist[k + 2] * NREC;
                    const float* q3 = WiT + (size_t)ilist[k + 3] * NREC;
                    const float N0 = q0[tid], M0 = q0[tid + 1024];   // next batch in flight
                    const float N1 = q1[tid], M1 = q1[tid + 1024];
                    const float N2 = q2[tid], M2 = q2[tid + 1024];
                    const float N3 = q3[tid], M3 = q3[tid + 1024];
                    curA += (double)A0; curA += (double)A1; curA += (double)A2; curA += (double)A3;
                    curB += (double)B0; curB += (double)B1; curB += (double)B2; curB += (double)B3;
                    A0 = N0; A1 = N1; A2 = N2; A3 = N3;
                    B0 = M0; B1 = M1; B2 = M2; B3 = M3;
                }
                curA += (double)A0; curA += (double)A1; curA += (double)A2; curA += (double)A3;
                curB += (double)B0; curB += (double)B1; curB += (double)B2; curB += (double)B3;
            }
            for (; k < itot; ++k) {
                const float* r0 = WiT + (size_t)ilist[k] * NREC;
                curA += (double)r0[tid];
                curB += (double)r0[tid + 1024];
            }
        }
        curA += brA; curB += brB;

        memA = memA * rec_c + curA;
        memB = memB * rec_c + curB;
        const bool zA = (memA - thr) > 0.0;
        const bool zB = (memB - thr) > 0.0;
        if (zA) memA -= thr;
        if (zB) memB -= thr;
        gA = gA * out_c + (zA ? 1.0 : 0.0);
        gB = gB * out_c + (zB ? 1.0 : 0.0);

        const unsigned long long mA = __ballot(zA);
        const unsigned long long mB = __ballot(zB);
        if (lane == 0) {
            zcnt[w]      = __popcll(mA);
            zcnt[16 + w] = __popcll(mB);
            unsigned* gm = spikeMask + (size_t)(t * BB + b) * 64;
            gm[2 * w]          = (unsigned)(mA & 0xFFFFFFFFu);
            gm[2 * w + 1]      = (unsigned)(mA >> 32);
            gm[32 + 2 * w]     = (unsigned)(mB & 0xFFFFFFFFu);
            gm[32 + 2 * w + 1] = (unsigned)(mB >> 32);
        }
        xv = xv_next;
        __syncthreads();                                  // S3

        int offA = 0, offB = 0, stot = 0;
        for (int j = 0; j < 32; ++j) {
            const int c = zcnt[j];
            if (j < w)      offA += c;
            if (j < 16 + w) offB += c;
            stot += c;
        }
        if (zA) slist[offA + lane_rank(mA)] = (unsigned short)tid;
        if (zB) slist[offB + lane_rank(mB)] = (unsigned short)(tid + 1024);
        __syncthreads();                                  // S4

        // ---- scatter: pipelined, 2 batches of 4 rows (16 loads) in flight ----
        if (t > 0) {
            int k = 0;
            if (stot >= 4) {
                size_t r0 = (size_t)slist[0] * NREC, r1 = (size_t)slist[1] * NREC;
                size_t r2 = (size_t)slist[2] * NREC, r3 = (size_t)slist[3] * NREC;
                float wA0 = WrT[r0 + tid], wB0 = WrT[r0 + tid + 1024];
                float wA1 = WrT[r1 + tid], wB1 = WrT[r1 + tid + 1024];
                float wA2 = WrT[r2 + tid], wB2 = WrT[r2 + tid + 1024];
                float wA3 = WrT[r3 + tid], wB3 = WrT[r3 + tid + 1024];
                int dA0 = dBp[r0 + tid], dB0 = dBp[r0 + tid + 1024];
                int dA1 = dBp[r1 + tid], dB1 = dBp[r1 + tid + 1024];
                int dA2 = dBp[r2 + tid], dB2 = dBp[r2 + tid + 1024];
                int dA3 = dBp[r3 + tid], dB3 = dBp[r3 + tid + 1024];
                for (k = 4; k + 4 <= stot; k += 4) {
                    const size_t s0 = (size_t)slist[k]     * NREC;
                    const size_t s1 = (size_t)slist[k + 1] * NREC;
                    const size_t s2 = (size_t)slist[k + 2] * NREC;
                    const size_t s3 = (size_t)slist[k + 3] * NREC;
                    const float nA0 = WrT[s0 + tid], nB0 = WrT[s0 + tid + 1024];
                    const float nA1 = WrT[s1 + tid], nB1 = WrT[s1 + tid + 1024];
                    const float nA2 = WrT[s2 + tid], nB2 = WrT[s2 + tid + 1024];
                    const float nA3 = WrT[s3 + tid], nB3 = WrT[s3 + tid + 1024];
                    const int eA0 = dBp[s0 + tid], eB0 = dBp[s0 + tid + 1024];
                    const int eA1 = dBp[s1 + tid], eB1 = dBp[s1 + tid + 1024];
                    const int eA2 = dBp[s2 + tid], eB2 = dBp[s2 + tid + 1024];
                    const int eA3 = dBp[s3 + tid], eB3 = dBp[s3 + tid + 1024];
                    // accumulate current batch while next batch is in flight
                    a0 += (dA0 == 1) ? (double)wA0 : 0.0; a1 += (dA0 == 2) ? (double)wA0 : 0.0;
                    a2 += (dA0 == 3) ? (double)wA0 : 0.0; a3 += (dA0 == 4) ? (double)wA0 : 0.0;
                    a0 += (dA1 == 1) ? (double)wA1 : 0.0; a1 += (dA1 == 2) ? (double)wA1 : 0.0;
                    a2 += (dA1 == 3) ? (double)wA1 : 0.0; a3 += (dA1 == 4) ? (double)wA1 : 0.0;
                    a0 += (dA2 == 1) ? (double)wA2 : 0.0; a1 += (dA2 == 2) ? (double)wA2 : 0.0;
                    a2 += (dA2 == 3) ? (double)wA2 : 0.0; a3 += (dA2 == 4) ? (double)wA2 : 0.0;
                    a0 += (dA3 == 1) ? (double)wA3 : 0.0; a1 += (dA3 == 2) ? (double)wA3 : 0.0;
                    a2 += (dA3 == 3) ? (double)wA3 : 0.0; a3 += (dA3 == 4) ? (double)wA3 : 0.0;
                    c0 += (dB0 == 1) ? (double)wB0 : 0.0; c1 += (dB0 == 2) ? (double)wB0 : 0.0;
                    c2 += (dB0 == 3) ? (double)wB0 : 0.0; c3 += (dB0 == 4) ? (double)wB0 : 0.0;
                    c0 += (dB1 == 1) ? (double)wB1 : 0.0; c1 += (dB1 == 2) ? (double)wB1 : 0.0;
                    c2 += (dB1 == 3) ? (double)wB1 : 0.0; c3 += (dB1 == 4) ? (double)wB1 : 0.0;
                    c0 += (dB2 == 1) ? (double)wB2 : 0.0; c1 += (dB2 == 2) ? (double)wB2 : 0.0;
                    c2 += (dB2 == 3) ? (double)wB2 : 0.0; c3 += (dB2 == 4) ? (double)wB2 : 0.0;
                    c0 += (dB3 == 1) ? (double)wB3 : 0.0; c1 += (dB3 == 2) ? (double)wB3 : 0.0;
                    c2 += (dB3 == 3) ? (double)wB3 : 0.0; c3 += (dB3 == 4) ? (double)wB3 : 0.0;
                    wA0 = nA0; wA1 = nA1; wA2 = nA2; wA3 = nA3;
                    wB0 = nB0; wB1 = nB1; wB2 = nB2; wB3 = nB3;
                    dA0 = eA0; dA1 = eA1; dA2 = eA2; dA3 = eA3;
                    dB0 = eB0; dB1 = eB1; dB2 = eB2; dB3 = eB3;
                }
                // final full batch
                a0 += (dA0 == 1) ? (double)wA0 : 0.0; a1 += (dA0 == 2) ? (double)wA0 : 0.0;
                a2 += (dA0 == 3) ? (double)wA0 : 0.0; a3 += (dA0 == 4) ? (double)wA0 : 0.0;
                a0 += (dA1 == 1) ? (double)wA1 : 0.0; a1 += (dA1 == 2) ? (double)wA1 : 0.0;
                a2 += (dA1 == 3) ? (double)wA1 : 0.0; a3 += (dA1 == 4) ? (double)wA1 : 0.0;
                a0 += (dA2 == 1) ? (double)wA2 : 0.0; a1 += (dA2 == 2) ? (double)wA2 : 0.0;
                a2 += (dA2 == 3) ? (double)wA2 : 0.0; a3 += (dA2 == 4) ? (double)wA2 : 0.0;
                a0 += (dA3 == 1) ? (double)wA3 : 0.0; a1 += (dA3 == 2) ? (double)wA3 : 0.0;
                a2 += (dA3 == 3) ? (double)wA3 : 0.0; a3 += (dA3 == 4) ? (double)wA3 : 0.0;
                c0 += (dB0 == 1) ? (double)wB0 : 0.0; c1 += (dB0 == 2) ? (double)wB0 : 0.0;
                c2 += (dB0 == 3) ? (double)wB0 : 0.0; c3 += (dB0 == 4) ? (double)wB0 : 0.0;
                c0 += (dB1 == 1) ? (double)wB1 : 0.0; c1 += (dB1 == 2) ? (double)wB1 : 0.0;
                c2 += (dB1 == 3) ? (double)wB1 : 0.0; c3 += (dB1 == 4) ? (double)wB1 : 0.0;
                c0 += (dB2 == 1) ? (double)wB2 : 0.0; c1 += (dB2 == 2) ? (double)wB2 : 0.0;
                c2 += (dB2 == 3) ? (double)wB2 : 0.0; c3 += (dB2 == 4) ? (double)wB2 : 0.0;
                c0 += (dB3 == 1) ? (double)wB3 : 0.0; c1 += (dB3 == 2) ? (double)wB3 : 0.0;
                c2 += (dB3 == 3) ? (double)wB3 : 0.0; c3 += (dB3 == 4) ? (double)wB3 : 0.0;
            }
            for (; k < stot; ++k) {
                const size_t r0 = (size_t)slist[k] * NREC;
                const float wA = WrT[r0 + tid], wB = WrT[r0 + tid + 1024];
                const int dA = dBp[r0 + tid], dV = dBp[r0 + tid + 1024];
                a0 += (dA == 1) ? (double)wA : 0.0; a1 += (dA == 2) ? (double)wA : 0.0;
                a2 += (dA == 3) ? (double)wA : 0.0; a3 += (dA == 4) ? (double)wA : 0.0;
                c0 += (dV == 1) ? (double)wB : 0.0; c1 += (dV == 2) ? (double)wB : 0.0;
                c2 += (dV == 3) ? (double)wB : 0.0; c3 += (dV == 4) ? (double)wB : 0.0;
            }
        }
    }

    g[(size_t)b * NREC + tid]        = gA;
    g[(size_t)b * NREC + tid + 1024] = gB;
}

__global__ __launch_bounds__(256) void k_memout(
    const double* __restrict__ g, const float* __restrict__ WoT,
    const float* __restrict__ Bo, const float* __restrict__ tau_out,
    float* __restrict__ mout)
{
    __shared__ double gs[NREC];
    const int b = blockIdx.x, tid = threadIdx.x;
#pragma unroll
    for (int k = 0; k < 8; ++k)
        gs[tid + 256 * k] = g[(size_t)b * NREC + tid + 256 * k];
    const double c = exp(-0.01 / (double)tau_out[0]);
    double S = 0.0;
    for (int t = 0; t < TT; ++t) S = S * c + 1.0;
    __syncthreads();
    if (tid < NOUT) {
        double a = 0.0;
        for (int n = 0; n < NREC; ++n)
            a += gs[n] * (double)WoT[n * NOUT + tid];
        a += (double)Bo[tid] * S;
        mout[(size_t)b * NOUT + tid] = (float)a;
    }
}

__global__ __launch_bounds__(256) void k_expand(
    const unsigned* __restrict__ spikeMask, float* __restrict__ zout)
{
    const int bid = blockIdx.x;
    const int b = bid >> 6, gw = bid & 63;
    const int t = threadIdx.x;
    if (t >= TT) return;
    const unsigned v = spikeMask[((size_t)(t * BB + b)) * 64 + gw];
    for (int j = 0; j < 32; ++j) {
        const int n = gw * 32 + j;
        zout[((size_t)b * NREC + n) * TT + t] = ((v >> j) & 1u) ? 1.0f : 0.0f;
    }
}

extern "C" void kernel_launch(void* const* d_in, const int* in_sizes, int n_in,
                              void* d_out, int out_size, void* d_ws, size_t ws_size,
                              hipStream_t stream) {
    const float *x = nullptr, *Wi = nullptr, *Wo = nullptr, *Br = nullptr, *Bo = nullptr;
    const void* c4[2] = {nullptr, nullptr};
    const float* sc[3] = {nullptr, nullptr, nullptr};
    int n4 = 0, nsc = 0;
    for (int i = 0; i < n_in; ++i) {
        switch (in_sizes[i]) {
            case 8192000: x  = (const float*)d_in[i]; break;
            case 1048576: Wi = (const float*)d_in[i]; break;
            case 262144:  Wo = (const float*)d_in[i]; break;
            case 2048:    Br = (const float*)d_in[i]; break;
            case 128:     Bo = (const float*)d_in[i]; break;
            case 4194304: if (n4 < 2)  c4[n4++]  = d_in[i]; break;
            case 1:       if (nsc < 3) sc[nsc++] = (const float*)d_in[i]; break;
            default: break;
        }
    }
    if (!x || !Wi || !Wo || !Br || !Bo || n4 < 2 || nsc < 3) {
        x  = (const float*)d_in[0];
        c4[0] = d_in[1];
        Wi = (const float*)d_in[2];
        c4[1] = d_in[3];
        Wo = (const float*)d_in[4];
        Br = (const float*)d_in[5];
        Bo = (const float*)d_in[6];
        sc[0] = (const float*)d_in[7];
        sc[1] = (const float*)d_in[8];
        sc[2] = (const float*)d_in[9];
    }
    const float* taur = sc[0];
    const float* tauo = sc[1];
    const float* thr  = sc[2];

    float* out = (float*)d_out;
    char* ws = (char*)d_ws;
    float*          WrT  = (float*)(ws + OFF_WRT);
    unsigned char*  dBp  = (unsigned char*)(ws + OFF_DB);
    float*          WiT  = (float*)(ws + OFF_WIT);
    float*          WoT  = (float*)(ws + OFF_WOT);
    unsigned*       mask = (unsigned*)(ws + OFF_MASK);
    double*         g    = (double*)(ws + OFF_G);

    hipLaunchKernelGGL(k_prep, dim3((NREC * NREC + 255) / 256), dim3(256), 0, stream,
                       c4[0], c4[1], Wi, Wo, WrT, dBp, WiT, WoT);
    hipLaunchKernelGGL(k_main, dim3(BB), dim3(1024), 0, stream,
                       x, WrT, dBp, WiT, Br, taur, tauo, thr, mask, g);
    hipLaunchKernelGGL(k_memout, dim3(BB), dim3(256), 0, stream,
                       g, WoT, Bo, tauo, out);
    hipLaunchKernelGGL(k_expand, dim3(BB * 64), dim3(256), 0, stream,
                       mask, out + 8192);
}

// Round 13
// 5467.389 us; speedup vs baseline: 1.3694x; 1.3694x over previous
//
#include <hip/hip_runtime.h>

#define NIN  512
#define NREC 2048
#define NOUT 128
#define BB   64
#define TT   250

// OUTPUTS ARE FLOAT32 (R9 probe). Semantics: JAX text (R10 PASS, absmax 0.0078125).
// ---- d_ws layout (~31.4 MB; 34.5 MB verified safe) ----
#define OFF_WRT  0UL          // f32 W_r^T [n][m]      16,777,216
#define OFF_DB   16777216UL   // u8  delays [n][m]      4,194,304
#define OFF_WIT  20971520UL   // f32 W_i^T [i][m]       4,194,304
#define OFF_WOT  25165824UL   // f32 W_o^T [n][o]       1,048,576
#define OFF_MASK 26214400UL   // u32 masks [t*64+b][64] 4,096,000
#define OFF_G    30310400UL   // f64 g[b][n]            1,048,576
#define OFF_CNT  31358976UL   // u32 cnt[t*64+b]           64,000 (memset 0 per launch)

__device__ __forceinline__ int decode_delay(int v) {
    if (v >= 0 && v <= 4) return v;
    const float f = __int_as_float(v);
    if (f >= 0.5f && f <= 4.5f) return (int)(f + 0.5f);
    return 0;
}
__device__ __forceinline__ int delay_like(int v) {
    if (v >= 0 && v <= 4) return 1;
    const float f = __int_as_float(v);
    return (f >= 0.5f && f <= 4.5f) ? 1 : 0;
}
__device__ __forceinline__ unsigned lane_rank(unsigned long long m) {
    unsigned r = __builtin_amdgcn_mbcnt_lo((unsigned)m, 0u);
    return __builtin_amdgcn_mbcnt_hi((unsigned)(m >> 32), r);
}

__global__ __launch_bounds__(256) void k_prep(
    const void* __restrict__ c4A, const void* __restrict__ c4B,
    const float* __restrict__ Wi, const float* __restrict__ Wo,
    float* __restrict__ WrT, unsigned char* __restrict__ dBp,
    float* __restrict__ WiT, float* __restrict__ WoT)
{
    const int* iA = (const int*)c4A;
    const int* iB = (const int*)c4B;
    int cntA = 0, cntB = 0;
    for (int j = 0; j < 64; ++j) { cntA += delay_like(iA[j]); cntB += delay_like(iB[j]); }
    const int*   dl = (cntA >= cntB) ? iA : iB;
    const float* Wr = (cntA >= cntB) ? (const float*)c4B : (const float*)c4A;

    const int idx = blockIdx.x * 256 + threadIdx.x;
    if (idx < NREC * NREC) {
        const int n = idx >> 11, m = idx & 2047;
        WrT[idx] = Wr[(size_t)m * NREC + n];                 // W_rT[n][m] = W_r[m][n]
        dBp[idx] = (unsigned char)decode_delay(dl[idx]);     // delays[n][m] natural
    }
    if (idx < NIN * NREC) {
        const int i = idx >> 11, m = idx & 2047;
        WiT[idx] = Wi[(size_t)m * NIN + i];                  // W_iT[i][m]
    }
    if (idx < NREC * NOUT) {
        const int n = idx >> 7, o = idx & 127;
        WoT[idx] = Wo[(size_t)o * NREC + n];                 // W_oT[n][o]
    }
}

// R13: 256 blocks x 512 threads. Block (b,q) owns neuron columns
// [512q, 512q+512) of batch b (1 neuron/thread). Per-step spike exchange
// among the 4 sibling blocks via spikeMask (agent-scope atomics) + a
// per-(t,b) release/acquire counter. All 256 blocks are resident by
// capacity (8 waves/block << 32 slots/CU), so the spin cannot deadlock.
__global__ __launch_bounds__(512) void k_main(
    const float* __restrict__ x,
    const float* __restrict__ WrT, const unsigned char* __restrict__ dBp,
    const float* __restrict__ WiT,
    const float* __restrict__ Br,
    const float* __restrict__ tau_rec, const float* __restrict__ tau_out,
    const float* __restrict__ thr_rec,
    unsigned* __restrict__ spikeMask, unsigned* __restrict__ cnt,
    double* __restrict__ g)
{
    __shared__ int icnt[8];
    __shared__ unsigned short ilist[NIN];
    __shared__ unsigned myw[16];
    __shared__ unsigned words[64];
    __shared__ int zcnt[64];
    __shared__ int zoff[64];
    __shared__ unsigned short slist[NREC];

    // XCD swizzle (blockIdx % 8 ~ XCD): same-q blocks land on XCD pairs,
    // maximizing L2 reuse of the per-q weight column slice. Coverage: each
    // (b,q) pair exactly once. Heuristic only — correctness independent.
    const int gid = blockIdx.x;
    const int r8  = gid & 7, kk = gid >> 3;
    const int q   = r8 >> 1;
    const int b   = kk * 2 + (r8 & 1);
    const int tid  = threadIdx.x;
    const int w    = tid >> 6;
    const int lane = tid & 63;
    const int col  = q * 512 + tid;          // my neuron (global id)

    const double rec_c = exp(-0.01 / (double)tau_rec[0]);
    const double out_c = exp(-0.01 / (double)tau_out[0]);
    const double thr   = (double)thr_rec[0];
    const double br    = (double)Br[col];
    double mem = 0.0, gacc = 0.0;
    double a0 = 0.0, a1 = 0.0, a2 = 0.0, a3 = 0.0;   // register delay ring

    const float* xb = x + (size_t)b * NIN * TT;      // x[b][i][t]
    float xv = xb[(size_t)tid * TT];                 // tid < 512 == NIN

    for (int t = 0; t < TT; ++t) {
        // consume current scheduled for this step, rotate ring
        double cur = a0; a0 = a1; a1 = a2; a2 = a3; a3 = 0.0;

        // ---- input spike ballot (all 512 inputs = all 512 threads) ----
        const bool ihit = (xv != 0.f);
        const unsigned long long im = __ballot(ihit);
        if (lane == 0) icnt[w] = __popcll(im);
        float xv_next = 0.f;
        if (t + 1 < TT) xv_next = xb[(size_t)tid * TT + (t + 1)];
        __syncthreads();                               // B1: icnt ready
        int ioffw = 0, itot = 0;
#pragma unroll
        for (int j = 0; j < 8; ++j) { const int c = icnt[j]; if (j < w) ioffw += c; itot += c; }
        if (ihit) ilist[ioffw + lane_rank(im)] = (unsigned short)tid;
        __syncthreads();                               // B2: ilist ready

        // ---- input gather over my column slice (unroll-4) ----
        {
            int k = 0;
            for (; k + 4 <= itot; k += 4) {
                const float v0 = WiT[(size_t)ilist[k]     * NREC + col];
                const float v1 = WiT[(size_t)ilist[k + 1] * NREC + col];
                const float v2 = WiT[(size_t)ilist[k + 2] * NREC + col];
                const float v3 = WiT[(size_t)ilist[k + 3] * NREC + col];
                cur += (double)v0; cur += (double)v1; cur += (double)v2; cur += (double)v3;
            }
            for (; k < itot; ++k) cur += (double)WiT[(size_t)ilist[k] * NREC + col];
        }
        cur += br;

        // ---- LIF update + spike + soft reset + output Horner ----
        mem = mem * rec_c + cur;
        const bool z = (mem - thr) > 0.0;
        if (z) mem -= thr;
        gacc = gacc * out_c + (z ? 1.0 : 0.0);

        // ---- publish my 16 mask words; release counter ----
        const unsigned long long mz = __ballot(z);
        if (lane == 0) {
            myw[2 * w]     = (unsigned)(mz & 0xFFFFFFFFu);
            myw[2 * w + 1] = (unsigned)(mz >> 32);
        }
        xv = xv_next;
        __syncthreads();                               // B3: myw ready
        unsigned* gm = spikeMask + (size_t)(t * BB + b) * 64;
        if (tid < 16)
            __hip_atomic_store(&gm[q * 16 + tid], myw[tid],
                               __ATOMIC_RELAXED, __HIP_MEMORY_SCOPE_AGENT);
        __syncthreads();                               // B4: vmcnt drained -> stores visible
        if (tid == 0) {
            __hip_atomic_fetch_add(&cnt[t * BB + b], 1u,
                                   __ATOMIC_RELEASE, __HIP_MEMORY_SCOPE_AGENT);
            if (t > 0) {                               // t=0 spikes never delivered
                while (__hip_atomic_load(&cnt[t * BB + b],
                                         __ATOMIC_ACQUIRE, __HIP_MEMORY_SCOPE_AGENT) < 4u)
                    __builtin_amdgcn_s_sleep(1);
            }
        }
        __syncthreads();                               // B5: all 4 siblings published

        if (t > 0) {
            // ---- read all 64 words, build slist (ascending => deterministic) ----
            if (tid < 64) {
                const unsigned wv = __hip_atomic_load(&gm[tid],
                                        __ATOMIC_RELAXED, __HIP_MEMORY_SCOPE_AGENT);
                words[tid] = wv;
                zcnt[tid]  = __popc(wv);
            }
            __syncthreads();                           // B6: words/zcnt ready
            if (tid < 64) {
                int off = 0;
                for (int j = 0; j < tid; ++j) off += zcnt[j];
                zoff[tid] = off;
            }
            __syncthreads();                           // B7: zoff ready
            const int stot = zoff[63] + zcnt[63];
            if (tid < 64) {
                unsigned bits = words[tid];
                int off = zoff[tid];
                while (bits) {
                    const int bp = __ffs(bits) - 1;
                    bits &= bits - 1;
                    slist[off++] = (unsigned short)(tid * 32 + bp);
                }
            }
            __syncthreads();                           // B8: slist ready

            // ---- scatter into register ring (unroll-4, R11-style) ----
            int k = 0;
            for (; k + 4 <= stot; k += 4) {
                const size_t r0 = (size_t)slist[k]     * NREC + col;
                const size_t r1 = (size_t)slist[k + 1] * NREC + col;
                const size_t r2 = (size_t)slist[k + 2] * NREC + col;
                const size_t r3 = (size_t)slist[k + 3] * NREC + col;
                const float w0 = WrT[r0]; const int d0 = dBp[r0];
                const float w1 = WrT[r1]; const int d1 = dBp[r1];
                const float w2 = WrT[r2]; const int d2 = dBp[r2];
                const float w3 = WrT[r3]; const int d3 = dBp[r3];
                a0 += (d0 == 1) ? (double)w0 : 0.0; a1 += (d0 == 2) ? (double)w0 : 0.0;
                a2 += (d0 == 3) ? (double)w0 : 0.0; a3 += (d0 == 4) ? (double)w0 : 0.0;
                a0 += (d1 == 1) ? (double)w1 : 0.0; a1 += (d1 == 2) ? (double)w1 : 0.0;
                a2 += (d1 == 3) ? (double)w1 : 0.0; a3 += (d1 == 4) ? (double)w1 : 0.0;
                a0 += (d2 == 1) ? (double)w2 : 0.0; a1 += (d2 == 2) ? (double)w2 : 0.0;
                a2 += (d2 == 3) ? (double)w2 : 0.0; a3 += (d2 == 4) ? (double)w2 : 0.0;
                a0 += (d3 == 1) ? (double)w3 : 0.0; a1 += (d3 == 2) ? (double)w3 : 0.0;
                a2 += (d3 == 3) ? (double)w3 : 0.0; a3 += (d3 == 4) ? (double)w3 : 0.0;
            }
            for (; k < stot; ++k) {
                const size_t r0 = (size_t)slist[k] * NREC + col;
                const float w0 = WrT[r0]; const int d0 = dBp[r0];
                a0 += (d0 == 1) ? (double)w0 : 0.0; a1 += (d0 == 2) ? (double)w0 : 0.0;
                a2 += (d0 == 3) ? (double)w0 : 0.0; a3 += (d0 == 4) ? (double)w0 : 0.0;
            }
        }
    }

    g[(size_t)b * NREC + col] = gacc;
}

__global__ __launch_bounds__(256) void k_memout(
    const double* __restrict__ g, const float* __restrict__ WoT,
    const float* __restrict__ Bo, const float* __restrict__ tau_out,
    float* __restrict__ mout)
{
    __shared__ double gs[NREC];
    const int b = blockIdx.x, tid = threadIdx.x;
#pragma unroll
    for (int k = 0; k < 8; ++k)
        gs[tid + 256 * k] = g[(size_t)b * NREC + tid + 256 * k];
    const double c = exp(-0.01 / (double)tau_out[0]);
    double S = 0.0;
    for (int t = 0; t < TT; ++t) S = S * c + 1.0;
    __syncthreads();
    if (tid < NOUT) {
        double a = 0.0;
        for (int n = 0; n < NREC; ++n)
            a += gs[n] * (double)WoT[n * NOUT + tid];
        a += (double)Bo[tid] * S;
        mout[(size_t)b * NOUT + tid] = (float)a;
    }
}

__global__ __launch_bounds__(256) void k_expand(
    const unsigned* __restrict__ spikeMask, float* __restrict__ zout)
{
    const int bid = blockIdx.x;
    const int b = bid >> 6, gw = bid & 63;
    const int t = threadIdx.x;
    if (t >= TT) return;
    const unsigned v = spikeMask[((size_t)(t * BB + b)) * 64 + gw];
    for (int j = 0; j < 32; ++j) {
        const int n = gw * 32 + j;
        zout[((size_t)b * NREC + n) * TT + t] = ((v >> j) & 1u) ? 1.0f : 0.0f;
    }
}

extern "C" void kernel_launch(void* const* d_in, const int* in_sizes, int n_in,
                              void* d_out, int out_size, void* d_ws, size_t ws_size,
                              hipStream_t stream) {
    const float *x = nullptr, *Wi = nullptr, *Wo = nullptr, *Br = nullptr, *Bo = nullptr;
    const void* c4[2] = {nullptr, nullptr};
    const float* sc[3] = {nullptr, nullptr, nullptr};
    int n4 = 0, nsc = 0;
    for (int i = 0; i < n_in; ++i) {
        switch (in_sizes[i]) {
            case 8192000: x  = (const float*)d_in[i]; break;
            case 1048576: Wi = (const float*)d_in[i]; break;
            case 262144:  Wo = (const float*)d_in[i]; break;
            case 2048:    Br = (const float*)d_in[i]; break;
            case 128:     Bo = (const float*)d_in[i]; break;
            case 4194304: if (n4 < 2)  c4[n4++]  = d_in[i]; break;
            case 1:       if (nsc < 3) sc[nsc++] = (const float*)d_in[i]; break;
            default: break;
        }
    }
    if (!x || !Wi || !Wo || !Br || !Bo || n4 < 2 || nsc < 3) {
        x  = (const float*)d_in[0];
        c4[0] = d_in[1];
        Wi = (const float*)d_in[2];
        c4[1] = d_in[3];
        Wo = (const float*)d_in[4];
        Br = (const float*)d_in[5];
        Bo = (const float*)d_in[6];
        sc[0] = (const float*)d_in[7];
        sc[1] = (const float*)d_in[8];
        sc[2] = (const float*)d_in[9];
    }
    const float* taur = sc[0];
    const float* tauo = sc[1];
    const float* thr  = sc[2];

    float* out = (float*)d_out;
    char* ws = (char*)d_ws;
    float*          WrT  = (float*)(ws + OFF_WRT);
    unsigned char*  dBp  = (unsigned char*)(ws + OFF_DB);
    float*          WiT  = (float*)(ws + OFF_WIT);
    float*          WoT  = (float*)(ws + OFF_WOT);
    unsigned*       mask = (unsigned*)(ws + OFF_MASK);
    double*         g    = (double*)(ws + OFF_G);
    unsigned*       cnt  = (unsigned*)(ws + OFF_CNT);

    hipMemsetAsync(cnt, 0, (size_t)TT * BB * sizeof(unsigned), stream);
    hipLaunchKernelGGL(k_prep, dim3((NREC * NREC + 255) / 256), dim3(256), 0, stream,
                       c4[0], c4[1], Wi, Wo, WrT, dBp, WiT, WoT);
    hipLaunchKernelGGL(k_main, dim3(256), dim3(512), 0, stream,
                       x, WrT, dBp, WiT, Br, taur, tauo, thr, mask, cnt, g);
    hipLaunchKernelGGL(k_memout, dim3(BB), dim3(256), 0, stream,
                       g, WoT, Bo, tauo, out);
    hipLaunchKernelGGL(k_expand, dim3(BB * 64), dim3(256), 0, stream,
                       mask, out + 8192);
}